// Round 8
// baseline (455.723 us; speedup 1.0000x reference)
//
#include <hip/hip_runtime.h>

#define CH    128
#define HH    64
#define WW    96
#define MD    40
#define KD    81
#define HW    (HH*WW)          /* 6144 */
#define CHW   (CH*HW)
#define SCALE 0.08838834764831845f   /* 1/sqrt(128) */
#define LSTR  72               /* ushorts per row: 64 bf16 + 8 pad (2-way frag reads) */
#define CHUNK (WW*LSTR)        /* 6912 ushorts = 13824 B per (b,y,h) per tensor */
#define WS2_USH ((size_t)2*HH*2*CHUNK)  /* x2 region offset in ushorts */
#define NCH   16               /* dy strided chunks */
#define NWG   (2*HH*NCH)       /* 2048 blocks */

typedef __attribute__((ext_vector_type(8))) short bf16x8;
typedef __attribute__((ext_vector_type(4))) float f32x4;

__device__ inline unsigned int pack2bf(float lo, float hi) {
    unsigned int a = __float_as_uint(lo), b = __float_as_uint(hi);
    a = (a + 0x7FFFu + ((a >> 16) & 1u)) >> 16;   // RTN bf16
    b = (b + 0x7FFFu + ((b >> 16) & 1u)) >> 16;
    return a | (b << 16);
}

__device__ __forceinline__ void gload16(const void* g, void* l) {
    __builtin_amdgcn_global_load_lds(
        (const __attribute__((address_space(1))) void*)g,
        (__attribute__((address_space(3))) void*)l, 16, 0, 0);
}

// ---------------------------------------------------------------------------
// Pre-pass: transpose+convert x1,x2 rows to bf16 workspace, [b][y][h][x][72].
// ---------------------------------------------------------------------------
__global__ __launch_bounds__(256) void prepack(
    const float* __restrict__ x1, const float* __restrict__ x2,
    unsigned short* __restrict__ ws)
{
    const int y = blockIdx.x;
    const int h = blockIdx.y & 1;
    const int t = blockIdx.y >> 1;
    const int b = blockIdx.z;

    const float* src = (t ? x2 : x1)
        + (size_t)b * CHW + (size_t)(h * 64) * HW + (size_t)y * WW;
    unsigned short* dst = ws + (size_t)t * WS2_USH
        + ((size_t)(b * HH + y) * 2 + h) * CHUNK;

    for (int j = threadIdx.x; j < 8 * WW; j += 256) {   // 3 iters
        const int cg = j / WW;                          // channel octet 0..7
        const int x  = j - cg * WW;
        const float* p = src + (size_t)(cg * 8) * HW + x;
        float f[8];
        #pragma unroll
        for (int i = 0; i < 8; ++i) f[i] = p[(size_t)i * HW];
        uint4 w;
        w.x = pack2bf(f[0], f[1]); w.y = pack2bf(f[2], f[3]);
        w.z = pack2bf(f[4], f[5]); w.w = pack2bf(f[6], f[7]);
        *reinterpret_cast<uint4*>(&dst[(size_t)x * LSTR + cg * 8]) = w;
    }
}

// ---------------------------------------------------------------------------
// Main: persistent dy-loop blocks. Block = (b, c, y) handles dy = c+16k
// (~5 slabs). x1 fragments loaded ONCE into registers (48 VGPR), overlapped
// with the first x2 stage. Per slab: stage x2 (both halves, ONE vmcnt drain),
// 36 MFMA, band-folded sD in bf16 (aliases x2 region), linear emit.
// 4 barriers + 1 drain per slab (R6: 5 + 2, plus x1 re-staged 81x).
// LDS = 27648 B; occupancy 4 blocks/CU (VGPR-capped at 16 waves/CU anyway).
// ---------------------------------------------------------------------------
__global__ __launch_bounds__(256, 4) void corr_kernel(
    const unsigned short* __restrict__ ws, float* __restrict__ out)
{
    const int wg  = blockIdx.x;
    const int y   = wg & 63;           // fastest -> XCD round-robin over y
    const int c   = (wg >> 6) & 15;
    const int b   = wg >> 10;
    const int tid = threadIdx.x;

    // LDS: x2 row both halves [0,27648); sD bf16 [0,15552) aliases it.
    __shared__ __align__(16) char smem[2 * 2 * CHUNK];   // 27648 B
    unsigned short* sX2 = reinterpret_cast<unsigned short*>(smem);
    unsigned short* sD  = reinterpret_cast<unsigned short*>(smem);

    const int lane = tid & 63;
    const int wave = tid >> 6;
    const int m0   = (wave >> 1) * 48;   // x2-tile base
    const int n0   = (wave & 1) * 48;    // x-tile base
    const int lr   = lane & 15;
    const int q    = lane >> 4;

    // Persistent x1 fragments in registers [h][kk][j]: 12 x bf16x8 = 48 VGPR.
    // Issued first; compiler's waitcnt before first MFMA use overlaps these
    // with the first x2 stage.
    const unsigned short* wsA = ws + ((size_t)(b * HH + y) * 2) * CHUNK;
    bf16x8 xf[2][2][3];
    #pragma unroll
    for (int h = 0; h < 2; ++h)
        #pragma unroll
        for (int kk = 0; kk < 2; ++kk)
            #pragma unroll
            for (int j = 0; j < 3; ++j)
                xf[h][kk][j] = *reinterpret_cast<const bf16x8*>(
                    &wsA[h * CHUNK + (n0 + 16 * j + lr) * LSTR + kk * 32 + q * 8]);

    const unsigned short* wsB0 = ws + WS2_USH + ((size_t)b * HH * 2) * CHUNK;

    #pragma unroll 1
    for (int dy = c; dy < KD; dy += NCH) {
        float* outbase = out + ((size_t)b * (KD * KD) + (size_t)dy * KD) * HW
                             + (size_t)y * WW;
        const int y2 = y + dy - MD;

        if (y2 < 0 || y2 >= HH) {        // block-uniform: no LDS, no barriers
            const float4 z = make_float4(0.f, 0.f, 0.f, 0.f);
            #pragma unroll
            for (int it = 0; it < 8; ++it) {
                const int idx = it * 256 + tid;
                if (idx < KD * (WW / 4)) {              // 1944, STRIDED
                    const int dx = idx / 24;
                    const int x4 = idx - dx * 24;
                    *reinterpret_cast<float4*>(outbase + (size_t)dx * HW + x4 * 4) = z;
                }
            }
            continue;
        }

        __syncthreads();                 // prior emit reads done before restage

        // Stage x2 row, BOTH halves back-to-back: 1728 lane-loads of 16 B.
        const unsigned short* g2 = wsB0 + (size_t)y2 * 2 * CHUNK;
        #pragma unroll
        for (int it = 0; it < 7; ++it) {
            const int idx = it * 256 + tid;
            if (idx < 2 * CHUNK / 8)                     // 1728
                gload16(g2 + (size_t)idx * 8, sX2 + (size_t)idx * 8);
        }
        __syncthreads();                 // the ONLY vmcnt(0) drain this slab

        f32x4 acc[3][3];
        #pragma unroll
        for (int i = 0; i < 3; ++i)
            #pragma unroll
            for (int j = 0; j < 3; ++j)
                acc[i][j] = (f32x4){0.f, 0.f, 0.f, 0.f};

        #pragma unroll
        for (int h = 0; h < 2; ++h) {
            #pragma unroll
            for (int kk = 0; kk < 2; ++kk) {
                const int cl = kk * 32 + q * 8;
                bf16x8 af[3];
                #pragma unroll
                for (int i = 0; i < 3; ++i)
                    af[i] = *reinterpret_cast<const bf16x8*>(
                        &sX2[h * CHUNK + (m0 + 16 * i + lr) * LSTR + cl]);
                #pragma unroll
                for (int i = 0; i < 3; ++i)
                    #pragma unroll
                    for (int j = 0; j < 3; ++j)
                        acc[i][j] = __builtin_amdgcn_mfma_f32_16x16x32_bf16(
                            af[i], xf[h][kk][j], acc[i][j], 0, 0, 0);
            }
        }
        __syncthreads();                 // x2 frag reads done; region -> sD

        // D layout: col = lane&15 (=x), row = q*4+r (=x2 in tile).
        // Band-fold dx = x2-x+40, keep 0..80; SCALE folded; bf16 store.
        // Swizzle bit3 (ushort units) = byte bit4: q-pairs 2-way alias -> free.
        #pragma unroll
        for (int i = 0; i < 3; ++i) {
            #pragma unroll
            for (int j = 0; j < 3; ++j) {
                const int col  = n0 + 16 * j + lr;
                const int rowb = m0 + 16 * i + q * 4;
                #pragma unroll
                for (int r = 0; r < 4; ++r) {
                    const int dxv = (rowb + r) - col + MD;
                    if ((unsigned)dxv < (unsigned)KD) {
                        const unsigned int u =
                            __float_as_uint(acc[i][j][r] * SCALE);
                        const unsigned short h16 = (unsigned short)
                            ((u + 0x7FFFu + ((u >> 16) & 1u)) >> 16);
                        sD[(dxv * WW + col) ^ (((dxv >> 2) & 1) << 3)] = h16;
                    }
                }
            }
        }
        __syncthreads();

        // Emit 81x96: 1944 quad-items; uint2 = 4 bf16 -> float4 store.
        int dx = tid / 24;
        int x  = 4 * (tid - dx * 24);
        #pragma unroll
        for (int it = 0; it < 8; ++it) {
            if (it < 7 || tid < 152) {   // 1944 = 7*256 + 152
                const int w = (dx * WW + x) ^ (((dx >> 2) & 1) << 3);
                const uint2 pv = *reinterpret_cast<const uint2*>(&sD[w]);
                float4 v;
                v.x = __uint_as_float(pv.x << 16);
                v.y = __uint_as_float(pv.x & 0xFFFF0000u);
                v.z = __uint_as_float(pv.y << 16);
                v.w = __uint_as_float(pv.y & 0xFFFF0000u);
                const int x2b = x + dx - MD;
                v.x = ((unsigned)(x2b + 0) < (unsigned)WW) ? v.x : 0.f;
                v.y = ((unsigned)(x2b + 1) < (unsigned)WW) ? v.y : 0.f;
                v.z = ((unsigned)(x2b + 2) < (unsigned)WW) ? v.z : 0.f;
                v.w = ((unsigned)(x2b + 3) < (unsigned)WW) ? v.w : 0.f;
                *reinterpret_cast<float4*>(outbase + (size_t)(dx * HW + x)) = v;
            }
            x += 64; dx += 10;           // +1024 floats = 10 rows + 64
            if (x >= WW) { x -= WW; ++dx; }
        }
    }
}

extern "C" void kernel_launch(void* const* d_in, const int* in_sizes, int n_in,
                              void* d_out, int out_size, void* d_ws, size_t ws_size,
                              hipStream_t stream) {
    const float* x1 = (const float*)d_in[0];
    const float* x2 = (const float*)d_in[1];
    float* out = (float*)d_out;
    unsigned short* ws = (unsigned short*)d_ws;

    hipLaunchKernelGGL(prepack, dim3(HH, 4, 2), dim3(256), 0, stream, x1, x2, ws);

    hipLaunchKernelGGL(corr_kernel, dim3(NWG), dim3(256), 0, stream, ws, out);
}